// Round 1
// baseline (537.888 us; speedup 1.0000x reference)
//
#include <hip/hip_runtime.h>

#define B_TOT 32768
#define NF    64
#define NB    33
#define NSEG  32   // NB-1
#define E     64
#define BPB   256  // b-rows per block

__global__ __launch_bounds__(256) void pwl_kernel(
    const float* __restrict__ X,       // [B, NF]
    const float* __restrict__ bounds,  // [NF, NB]
    const float* __restrict__ W,       // [NF, NSEG, E]
    const float* __restrict__ bias,    // [NF, E]
    float* __restrict__ out)           // [B, NF*E]
{
    __shared__ __align__(16) float sW[NSEG][E];   // 8 KB
    __shared__ __align__(16) float sP[NB][E];     // 8.25 KB prefix (incl. bias)
    __shared__ float sBounds[NB];
    __shared__ float sFrac[BPB];
    __shared__ int   sJ[BPB];

    const int f   = blockIdx.x;        // f fastest -> same-b0 blocks co-resident
    const int tid = threadIdx.x;
    const int b0  = blockIdx.y * BPB;

    // ---- stage W[f] (2048 floats = 512 float4) and bounds[f] ----
    {
        const float4* Wg  = reinterpret_cast<const float4*>(W + f * (NSEG * E));
        float4*       sW4 = reinterpret_cast<float4*>(&sW[0][0]);
        sW4[tid]       = Wg[tid];
        sW4[tid + 256] = Wg[tid + 256];
        if (tid < NB) sBounds[tid] = bounds[f * NB + tid];
    }
    __syncthreads();

    // ---- prefix sums P[j][e] = bias[e] + sum_{i<j} W[i][e] ----
    if (tid < E) {
        float acc = bias[f * E + tid];
        sP[0][tid] = acc;
        #pragma unroll
        for (int i = 0; i < NSEG; ++i) {
            acc += sW[i][tid];
            sP[i + 1][tid] = acc;
        }
    }
    __syncthreads();

    // ---- phase A: bucket one x per thread ----
    {
        const float x = X[(b0 + tid) * NF + f];
        int c = 0;
        #pragma unroll
        for (int i = 0; i < NB; ++i) c += (sBounds[i] <= x) ? 1 : 0;
        int j = c - 1;
        j = (j < 0) ? 0 : ((j > NSEG - 1) ? NSEG - 1 : j);
        const float lo = sBounds[j];
        const float hi = sBounds[j + 1];
        float fr = (x - lo) / (hi - lo);
        fr = fminf(fmaxf(fr, 0.0f), 1.0f);
        sJ[tid]   = j;
        sFrac[tid] = fr;
    }
    __syncthreads();

    // ---- phase B: 16 threads per b-row, float4 each ----
    const int q = tid & 15;     // e-quarter: e = 4q..4q+3
    const int g = tid >> 4;     // 0..15
    const float4* sP4 = reinterpret_cast<const float4*>(&sP[0][0]);
    const float4* sW4 = reinterpret_cast<const float4*>(&sW[0][0]);
    float4* out4 = reinterpret_cast<float4*>(out);
    const int colbase = f * (E / 4) + q;   // within a 1024-float4 row

    #pragma unroll 4
    for (int k = 0; k < 16; ++k) {
        const int idx = k * 16 + g;        // b offset within chunk
        const int   j  = sJ[idx];
        const float fr = sFrac[idx];
        const float4 p = sP4[j * 16 + q];
        const float4 w = sW4[j * 16 + q];
        float4 r;
        r.x = fmaxf(fmaf(fr, w.x, p.x), 0.0f);
        r.y = fmaxf(fmaf(fr, w.y, p.y), 0.0f);
        r.z = fmaxf(fmaf(fr, w.z, p.z), 0.0f);
        r.w = fmaxf(fmaf(fr, w.w, p.w), 0.0f);
        out4[(b0 + idx) * (NF * E / 4) + colbase] = r;
    }
}

extern "C" void kernel_launch(void* const* d_in, const int* in_sizes, int n_in,
                              void* d_out, int out_size, void* d_ws, size_t ws_size,
                              hipStream_t stream) {
    const float* X      = (const float*)d_in[0];
    const float* bounds = (const float*)d_in[1];
    const float* W      = (const float*)d_in[2];
    const float* bias   = (const float*)d_in[3];
    float* out          = (float*)d_out;

    dim3 grid(NF, B_TOT / BPB);   // (64, 128)
    dim3 block(256);
    pwl_kernel<<<grid, block, 0, stream>>>(X, bounds, W, bias, out);
}